// Round 4
// baseline (228.889 us; speedup 1.0000x reference)
//
#include <hip/hip_runtime.h>
#include <math.h>

#define DIM 128
#define NVOX (DIM*DIM*DIM)

// ---- per-voxel Jacobian (np.gradient semantics) + trilinear warp ------------
__device__ __forceinline__ void jac_warp(const float* __restrict__ dti,
                                         const float* __restrict__ ddf,
                                         int id, float J[9], float w[6])
{
    const int k = id & (DIM - 1);
    const int j = (id >> 7) & (DIM - 1);
    const int i = id >> 14;

    const int im = (i > 0) ? i - 1 : 0, ip = (i < DIM - 1) ? i + 1 : DIM - 1;
    const int jm = (j > 0) ? j - 1 : 0, jp = (j < DIM - 1) ? j + 1 : DIM - 1;
    const int km = (k > 0) ? k - 1 : 0, kp = (k < DIM - 1) ? k + 1 : DIM - 1;
    const float si = (ip - im == 2) ? 0.5f : 1.0f;
    const float sj = (jp - jm == 2) ? 0.5f : 1.0f;
    const float sk = (kp - km == 2) ? 0.5f : 1.0f;

    const int l_ip = (ip << 14) | (j << 7) | k;
    const int l_im = (im << 14) | (j << 7) | k;
    const int l_jp = (i << 14) | (jp << 7) | k;
    const int l_jm = (i << 14) | (jm << 7) | k;
    const int l_kp = (i << 14) | (j << 7) | kp;
    const int l_km = (i << 14) | (j << 7) | km;

    float u[3];
#pragma unroll
    for (int c = 0; c < 3; ++c) {
        const float* __restrict__ p = ddf + c * NVOX;
        u[c] = p[id];
        J[c * 3 + 0] = (p[l_ip] - p[l_im]) * si;
        J[c * 3 + 1] = (p[l_jp] - p[l_jm]) * sj;
        J[c * 3 + 2] = (p[l_kp] - p[l_km]) * sk;
        J[c * 3 + c] += 1.0f;
    }

    const float cx = fminf(fmaxf((float)i + u[0], 0.0f), (float)(DIM - 1));
    const float cy = fminf(fmaxf((float)j + u[1], 0.0f), (float)(DIM - 1));
    const float cz = fminf(fmaxf((float)k + u[2], 0.0f), (float)(DIM - 1));
    const float x0f = floorf(cx), y0f = floorf(cy), z0f = floorf(cz);
    const float fx = cx - x0f, fy = cy - y0f, fz = cz - z0f;
    const int x0 = (int)x0f, y0 = (int)y0f, z0 = (int)z0f;
    const int x1 = min(x0 + 1, DIM - 1);
    const int y1 = min(y0 + 1, DIM - 1);
    const int z1 = min(z0 + 1, DIM - 1);

    const int l000 = (x0 << 14) | (y0 << 7) | z0;
    const int l001 = (x0 << 14) | (y0 << 7) | z1;
    const int l010 = (x0 << 14) | (y1 << 7) | z0;
    const int l011 = (x0 << 14) | (y1 << 7) | z1;
    const int l100 = (x1 << 14) | (y0 << 7) | z0;
    const int l101 = (x1 << 14) | (y0 << 7) | z1;
    const int l110 = (x1 << 14) | (y1 << 7) | z0;
    const int l111 = (x1 << 14) | (y1 << 7) | z1;

#pragma unroll
    for (int c = 0; c < 6; ++c) {
        const float* __restrict__ p = dti + c * NVOX;
        const float c00 = p[l000] * (1.0f - fz) + p[l001] * fz;
        const float c01 = p[l010] * (1.0f - fz) + p[l011] * fz;
        const float c10 = p[l100] * (1.0f - fz) + p[l101] * fz;
        const float c11 = p[l110] * (1.0f - fz) + p[l111] * fz;
        const float c0 = c00 * (1.0f - fy) + c01 * fy;
        const float c1 = c10 * (1.0f - fy) + c11 * fy;
        w[c] = c0 * (1.0f - fx) + c1 * fx;
    }
}

// ---- fp32 polar factor: branch-free 3 scaled + 4 unscaled Newton ------------
// Fixed point: R = U @ Vh (SVD polar factor), sign(det) preserved.
// Returns bad=true for cond_F(J) > 2e3 (caller redoes in fp64).
__device__ __forceinline__ bool polar_f32(const float J[9], float X[9])
{
#pragma unroll
    for (int t = 0; t < 9; ++t) X[t] = J[t];
    bool bad = false;
#pragma unroll
    for (int it = 0; it < 7; ++it) {
        float C[9];
        C[0] = X[4] * X[8] - X[5] * X[7];
        C[1] = X[5] * X[6] - X[3] * X[8];
        C[2] = X[3] * X[7] - X[4] * X[6];
        C[3] = X[2] * X[7] - X[1] * X[8];
        C[4] = X[0] * X[8] - X[2] * X[6];
        C[5] = X[1] * X[6] - X[0] * X[7];
        C[6] = X[1] * X[5] - X[2] * X[4];
        C[7] = X[2] * X[3] - X[0] * X[5];
        C[8] = X[0] * X[4] - X[1] * X[3];
        const float det = X[0] * C[0] + X[1] * C[1] + X[2] * C[2];
        float a, b;
        if (it < 3) {
            float nX = 0.0f, nC = 0.0f;
#pragma unroll
            for (int t = 0; t < 9; ++t) { nX += X[t] * X[t]; nC += C[t] * C[t]; }
            if (it == 0)
                bad = !(__builtin_amdgcn_sqrtf(nX * nC) < 2.0e3f * fabsf(det));
            // s = ||C||/||X||;  g = sqrt(s/|det|);  b = 0.5*g/s * sign(det)
            const float s = __builtin_amdgcn_sqrtf(nC * __builtin_amdgcn_rcpf(nX));
            const float g = __builtin_amdgcn_sqrtf(s * __builtin_amdgcn_rcpf(fabsf(det)));
            a = 0.5f * g;
            b = copysignf(0.5f * g * __builtin_amdgcn_rcpf(s), det);
        } else {
            a = 0.5f;
            b = 0.5f * __builtin_amdgcn_rcpf(det);
        }
#pragma unroll
        for (int t = 0; t < 9; ++t) X[t] = a * X[t] + b * C[t];
    }
    return bad;
}

// ---- fp64 fallback (rare; inline & unrolled => register-resident) -----------
__device__ __forceinline__ void polar_f64(const float J[9], float X[9])
{
    double Y[9];
#pragma unroll
    for (int t = 0; t < 9; ++t) Y[t] = (double)J[t];
    for (int it = 0; it < 20; ++it) {
        double C[9];
        C[0] = Y[4] * Y[8] - Y[5] * Y[7];
        C[1] = Y[5] * Y[6] - Y[3] * Y[8];
        C[2] = Y[3] * Y[7] - Y[4] * Y[6];
        C[3] = Y[2] * Y[7] - Y[1] * Y[8];
        C[4] = Y[0] * Y[8] - Y[2] * Y[6];
        C[5] = Y[1] * Y[6] - Y[0] * Y[7];
        C[6] = Y[1] * Y[5] - Y[2] * Y[4];
        C[7] = Y[2] * Y[3] - Y[0] * Y[5];
        C[8] = Y[0] * Y[4] - Y[1] * Y[3];
        const double det = Y[0] * C[0] + Y[1] * C[1] + Y[2] * C[2];
        if (!(fabs(det) > 1e-300)) break;
        double nX = 0.0, nC = 0.0;
#pragma unroll
        for (int t = 0; t < 9; ++t) { nX += Y[t] * Y[t]; nC += C[t] * C[t]; }
        const double g = sqrt(sqrt(nC) / (fabs(det) * sqrt(nX)));
        const double a = 0.5 * g;
        const double b = 0.5 / (g * det);
        double diff2 = 0.0, n2 = 0.0;
#pragma unroll
        for (int t = 0; t < 9; ++t) {
            const double y = a * Y[t] + b * C[t];
            const double d = y - Y[t];
            diff2 += d * d; n2 += y * y;
            Y[t] = y;
        }
        if (diff2 <= 1e-26 * n2) break;
    }
#pragma unroll
    for (int t = 0; t < 9; ++t) X[t] = (float)Y[t];
}

// ---- Dp = R^T M R, write 6 lower-tri channels -------------------------------
__device__ __forceinline__ void congruence_store(float* __restrict__ out,
                                                 int id, const float X[9],
                                                 const float w[6])
{
    const float M00 = w[0], M01 = w[1], M11 = w[2];
    const float M02 = w[3], M12 = w[4], M22 = w[5];
    float P[9];  // P = M * R
    P[0] = M00 * X[0] + M01 * X[3] + M02 * X[6];
    P[1] = M00 * X[1] + M01 * X[4] + M02 * X[7];
    P[2] = M00 * X[2] + M01 * X[5] + M02 * X[8];
    P[3] = M01 * X[0] + M11 * X[3] + M12 * X[6];
    P[4] = M01 * X[1] + M11 * X[4] + M12 * X[7];
    P[5] = M01 * X[2] + M11 * X[5] + M12 * X[8];
    P[6] = M02 * X[0] + M12 * X[3] + M22 * X[6];
    P[7] = M02 * X[1] + M12 * X[4] + M22 * X[7];
    P[8] = M02 * X[2] + M12 * X[5] + M22 * X[8];

    out[0 * NVOX + id] = X[0] * P[0] + X[3] * P[3] + X[6] * P[6];
    out[1 * NVOX + id] = X[1] * P[0] + X[4] * P[3] + X[7] * P[6];
    out[2 * NVOX + id] = X[1] * P[1] + X[4] * P[4] + X[7] * P[7];
    out[3 * NVOX + id] = X[2] * P[0] + X[5] * P[3] + X[8] * P[6];
    out[4 * NVOX + id] = X[2] * P[1] + X[5] * P[4] + X[8] * P[7];
    out[5 * NVOX + id] = X[2] * P[2] + X[5] * P[5] + X[8] * P[8];
}

__global__ __launch_bounds__(256) void warp_dti_kernel(
    const float* __restrict__ dti,
    const float* __restrict__ ddf,
    float* __restrict__ out)
{
    // 2 voxels per thread: block covers 512 contiguous voxels; both accesses
    // stay coalesced and L1-local; two independent straight-line Newton
    // chains give the scheduler ILP to hide the dependency latency.
    const int id0 = blockIdx.x * 512 + threadIdx.x;
    const int id1 = id0 + 256;

    float J0[9], w0[6], J1[9], w1[6];
    jac_warp(dti, ddf, id0, J0, w0);
    jac_warp(dti, ddf, id1, J1, w1);

    float R0[9], R1[9];
    const bool bad0 = polar_f32(J0, R0);
    const bool bad1 = polar_f32(J1, R1);
    if (__builtin_expect(bad0, 0)) polar_f64(J0, R0);
    if (__builtin_expect(bad1, 0)) polar_f64(J1, R1);

    congruence_store(out, id0, R0, w0);
    congruence_store(out, id1, R1, w1);
}

extern "C" void kernel_launch(void* const* d_in, const int* in_sizes, int n_in,
                              void* d_out, int out_size, void* d_ws, size_t ws_size,
                              hipStream_t stream) {
    const float* dti = (const float*)d_in[0];
    const float* ddf = (const float*)d_in[1];
    float* out = (float*)d_out;
    const int nblk = NVOX / 512;
    hipLaunchKernelGGL(warp_dti_kernel, dim3(nblk), dim3(256), 0, stream,
                       dti, ddf, out);
}

// Round 5
// 169.646 us; speedup vs baseline: 1.3492x; 1.3492x over previous
//
#include <hip/hip_runtime.h>
#include <hip/hip_fp16.h>
#include <math.h>

#define DIM 128
#define NVOX (DIM*DIM*DIM)

// ---------------- Pass A: dti (6,NVOX) f32 SoA -> AoS fp16 16B/voxel ---------
// Gather-side effect: one corner = one global_load_dwordx4 touching ONE cache
// line, instead of 6 scalar loads into 6 separate 8MB planes (R4 measured
// L1-transaction-bound at ~2400 lines/wave-voxel-set).
__global__ __launch_bounds__(256) void pack_dti_kernel(
    const float* __restrict__ dti, uint4* __restrict__ aos)
{
    const int id = blockIdx.x * 256 + threadIdx.x;
    const __half2 h01 = __floats2half2_rn(dti[0 * NVOX + id], dti[1 * NVOX + id]);
    const __half2 h23 = __floats2half2_rn(dti[2 * NVOX + id], dti[3 * NVOX + id]);
    const __half2 h45 = __floats2half2_rn(dti[4 * NVOX + id], dti[5 * NVOX + id]);
    uint4 q;
    q.x = *reinterpret_cast<const unsigned int*>(&h01);
    q.y = *reinterpret_cast<const unsigned int*>(&h23);
    q.z = *reinterpret_cast<const unsigned int*>(&h45);
    q.w = 0u;
    aos[id] = q;
}

// ---- fp32 polar factor: branch-free 3 scaled + 4 unscaled Newton ------------
// Fixed point: R = U @ Vh (SVD polar factor), sign(det) preserved.
// Returns bad=true for cond_F(J) > 2e3 (caller redoes in fp64).
__device__ __forceinline__ bool polar_f32(const float J[9], float X[9])
{
#pragma unroll
    for (int t = 0; t < 9; ++t) X[t] = J[t];
    bool bad = false;
#pragma unroll
    for (int it = 0; it < 7; ++it) {
        float C[9];
        C[0] = X[4] * X[8] - X[5] * X[7];
        C[1] = X[5] * X[6] - X[3] * X[8];
        C[2] = X[3] * X[7] - X[4] * X[6];
        C[3] = X[2] * X[7] - X[1] * X[8];
        C[4] = X[0] * X[8] - X[2] * X[6];
        C[5] = X[1] * X[6] - X[0] * X[7];
        C[6] = X[1] * X[5] - X[2] * X[4];
        C[7] = X[2] * X[3] - X[0] * X[5];
        C[8] = X[0] * X[4] - X[1] * X[3];
        const float det = X[0] * C[0] + X[1] * C[1] + X[2] * C[2];
        float a, b;
        if (it < 3) {
            float nX = 0.0f, nC = 0.0f;
#pragma unroll
            for (int t = 0; t < 9; ++t) { nX += X[t] * X[t]; nC += C[t] * C[t]; }
            if (it == 0)
                bad = !(__builtin_amdgcn_sqrtf(nX * nC) < 2.0e3f * fabsf(det));
            const float s = __builtin_amdgcn_sqrtf(nC * __builtin_amdgcn_rcpf(nX));
            const float g = __builtin_amdgcn_sqrtf(s * __builtin_amdgcn_rcpf(fabsf(det)));
            a = 0.5f * g;
            b = copysignf(0.5f * g * __builtin_amdgcn_rcpf(s), det);
        } else {
            a = 0.5f;
            b = 0.5f * __builtin_amdgcn_rcpf(det);
        }
#pragma unroll
        for (int t = 0; t < 9; ++t) X[t] = a * X[t] + b * C[t];
    }
    return bad;
}

// ---- fp64 fallback (rare; inline & unrolled => register-resident) -----------
__device__ __forceinline__ void polar_f64(const float J[9], float X[9])
{
    double Y[9];
#pragma unroll
    for (int t = 0; t < 9; ++t) Y[t] = (double)J[t];
    for (int it = 0; it < 20; ++it) {
        double C[9];
        C[0] = Y[4] * Y[8] - Y[5] * Y[7];
        C[1] = Y[5] * Y[6] - Y[3] * Y[8];
        C[2] = Y[3] * Y[7] - Y[4] * Y[6];
        C[3] = Y[2] * Y[7] - Y[1] * Y[8];
        C[4] = Y[0] * Y[8] - Y[2] * Y[6];
        C[5] = Y[1] * Y[6] - Y[0] * Y[7];
        C[6] = Y[1] * Y[5] - Y[2] * Y[4];
        C[7] = Y[2] * Y[3] - Y[0] * Y[5];
        C[8] = Y[0] * Y[4] - Y[1] * Y[3];
        const double det = Y[0] * C[0] + Y[1] * C[1] + Y[2] * C[2];
        if (!(fabs(det) > 1e-300)) break;
        double nX = 0.0, nC = 0.0;
#pragma unroll
        for (int t = 0; t < 9; ++t) { nX += Y[t] * Y[t]; nC += C[t] * C[t]; }
        const double g = sqrt(sqrt(nC) / (fabs(det) * sqrt(nX)));
        const double a = 0.5 * g;
        const double b = 0.5 / (g * det);
        double diff2 = 0.0, n2 = 0.0;
#pragma unroll
        for (int t = 0; t < 9; ++t) {
            const double y = a * Y[t] + b * C[t];
            const double d = y - Y[t];
            diff2 += d * d; n2 += y * y;
            Y[t] = y;
        }
        if (diff2 <= 1e-26 * n2) break;
    }
#pragma unroll
    for (int t = 0; t < 9; ++t) X[t] = (float)Y[t];
}

// ---------------- Pass B: warp + polar + congruence --------------------------
__global__ __launch_bounds__(256) void warp_dti_kernel(
    const uint4* __restrict__ aos,
    const float* __restrict__ ddf,
    float* __restrict__ out)
{
    const int id = blockIdx.x * 256 + threadIdx.x;
    const int k = id & (DIM - 1);
    const int j = (id >> 7) & (DIM - 1);
    const int i = id >> 14;

    // ---- Jacobian: J = I + grad(ddf) (np.gradient semantics) ----
    const int im = (i > 0) ? i - 1 : 0, ip = (i < DIM - 1) ? i + 1 : DIM - 1;
    const int jm = (j > 0) ? j - 1 : 0, jp = (j < DIM - 1) ? j + 1 : DIM - 1;
    const int km = (k > 0) ? k - 1 : 0, kp = (k < DIM - 1) ? k + 1 : DIM - 1;
    const float si = (ip - im == 2) ? 0.5f : 1.0f;
    const float sj = (jp - jm == 2) ? 0.5f : 1.0f;
    const float sk = (kp - km == 2) ? 0.5f : 1.0f;

    const int l_ip = (ip << 14) | (j << 7) | k;
    const int l_im = (im << 14) | (j << 7) | k;
    const int l_jp = (i << 14) | (jp << 7) | k;
    const int l_jm = (i << 14) | (jm << 7) | k;
    const int l_kp = (i << 14) | (j << 7) | kp;
    const int l_km = (i << 14) | (j << 7) | km;

    float J[9];
    float u[3];
#pragma unroll
    for (int c = 0; c < 3; ++c) {
        const float* __restrict__ p = ddf + c * NVOX;
        u[c] = p[id];
        J[c * 3 + 0] = (p[l_ip] - p[l_im]) * si;
        J[c * 3 + 1] = (p[l_jp] - p[l_jm]) * sj;
        J[c * 3 + 2] = (p[l_kp] - p[l_km]) * sk;
        J[c * 3 + c] += 1.0f;
    }

    // ---- Trilinear warp from fp16 AoS (border padding) ----
    const float cx = fminf(fmaxf((float)i + u[0], 0.0f), (float)(DIM - 1));
    const float cy = fminf(fmaxf((float)j + u[1], 0.0f), (float)(DIM - 1));
    const float cz = fminf(fmaxf((float)k + u[2], 0.0f), (float)(DIM - 1));
    const float x0f = floorf(cx), y0f = floorf(cy), z0f = floorf(cz);
    const float fx = cx - x0f, fy = cy - y0f, fz = cz - z0f;
    const int x0 = (int)x0f, y0 = (int)y0f, z0 = (int)z0f;
    const int x1 = min(x0 + 1, DIM - 1);
    const int y1 = min(y0 + 1, DIM - 1);
    const int z1 = min(z0 + 1, DIM - 1);

    const float gx0 = 1.0f - fx, gy0 = 1.0f - fy, gz0 = 1.0f - fz;

    float acc0 = 0.0f, acc1 = 0.0f, acc2 = 0.0f;
    float acc3 = 0.0f, acc4 = 0.0f, acc5 = 0.0f;

    auto gat = [&](int lin, float wt) {
        const uint4 q = aos[lin];
        const float2 f01 = __half22float2(*reinterpret_cast<const __half2*>(&q.x));
        const float2 f23 = __half22float2(*reinterpret_cast<const __half2*>(&q.y));
        const float2 f45 = __half22float2(*reinterpret_cast<const __half2*>(&q.z));
        acc0 = fmaf(wt, f01.x, acc0);
        acc1 = fmaf(wt, f01.y, acc1);
        acc2 = fmaf(wt, f23.x, acc2);
        acc3 = fmaf(wt, f23.y, acc3);
        acc4 = fmaf(wt, f45.x, acc4);
        acc5 = fmaf(wt, f45.y, acc5);
    };

    gat((x0 << 14) | (y0 << 7) | z0, gx0 * gy0 * gz0);
    gat((x0 << 14) | (y0 << 7) | z1, gx0 * gy0 * fz);
    gat((x0 << 14) | (y1 << 7) | z0, gx0 * fy * gz0);
    gat((x0 << 14) | (y1 << 7) | z1, gx0 * fy * fz);
    gat((x1 << 14) | (y0 << 7) | z0, fx * gy0 * gz0);
    gat((x1 << 14) | (y0 << 7) | z1, fx * gy0 * fz);
    gat((x1 << 14) | (y1 << 7) | z0, fx * fy * gz0);
    gat((x1 << 14) | (y1 << 7) | z1, fx * fy * fz);

    // ---- Polar factor ----
    float X[9];
    const bool bad = polar_f32(J, X);
    if (__builtin_expect(bad, 0)) polar_f64(J, X);

    // ---- Dp = R^T M R ----
    const float M00 = acc0, M01 = acc1, M11 = acc2;
    const float M02 = acc3, M12 = acc4, M22 = acc5;
    float P[9];  // P = M * R
    P[0] = M00 * X[0] + M01 * X[3] + M02 * X[6];
    P[1] = M00 * X[1] + M01 * X[4] + M02 * X[7];
    P[2] = M00 * X[2] + M01 * X[5] + M02 * X[8];
    P[3] = M01 * X[0] + M11 * X[3] + M12 * X[6];
    P[4] = M01 * X[1] + M11 * X[4] + M12 * X[7];
    P[5] = M01 * X[2] + M11 * X[5] + M12 * X[8];
    P[6] = M02 * X[0] + M12 * X[3] + M22 * X[6];
    P[7] = M02 * X[1] + M12 * X[4] + M22 * X[7];
    P[8] = M02 * X[2] + M12 * X[5] + M22 * X[8];

    out[0 * NVOX + id] = X[0] * P[0] + X[3] * P[3] + X[6] * P[6];
    out[1 * NVOX + id] = X[1] * P[0] + X[4] * P[3] + X[7] * P[6];
    out[2 * NVOX + id] = X[1] * P[1] + X[4] * P[4] + X[7] * P[7];
    out[3 * NVOX + id] = X[2] * P[0] + X[5] * P[3] + X[8] * P[6];
    out[4 * NVOX + id] = X[2] * P[1] + X[5] * P[4] + X[8] * P[7];
    out[5 * NVOX + id] = X[2] * P[2] + X[5] * P[5] + X[8] * P[8];
}

extern "C" void kernel_launch(void* const* d_in, const int* in_sizes, int n_in,
                              void* d_out, int out_size, void* d_ws, size_t ws_size,
                              hipStream_t stream) {
    const float* dti = (const float*)d_in[0];
    const float* ddf = (const float*)d_in[1];
    float* out = (float*)d_out;
    uint4* aos = (uint4*)d_ws;  // 2M voxels * 16 B = 32 MB scratch

    const int nblk = NVOX / 256;
    hipLaunchKernelGGL(pack_dti_kernel, dim3(nblk), dim3(256), 0, stream,
                       dti, aos);
    hipLaunchKernelGGL(warp_dti_kernel, dim3(nblk), dim3(256), 0, stream,
                       aos, ddf, out);
}

// Round 7
// 168.976 us; speedup vs baseline: 1.3546x; 1.0040x over previous
//
#include <hip/hip_runtime.h>
#include <hip/hip_fp16.h>
#include <math.h>

#define DIM 128
#define NVOX (DIM*DIM*DIM)

// clang native vector types (HIP's float4/uint4 are classes — rejected by
// __builtin_nontemporal_load/store)
typedef float vfloat4 __attribute__((ext_vector_type(4)));
typedef unsigned int vuint4 __attribute__((ext_vector_type(4)));

// ---------------- Pass A: dti (6,NVOX) f32 SoA -> AoS fp16 16B/voxel ---------
// One warp corner = one global_load_dwordx4 touching ONE cache line instead of
// 6 scalar loads into 6 separate 8MB planes (R4: L1-transaction-bound).
// 4 voxels/thread, nt loads (dti is dead after this pass; keep it out of
// L2/L3 so the aos array stays resident). Same XCD swizzle as pass B so each
// slab is written by the XCD that will gather from it.
__global__ __launch_bounds__(256) void pack_dti_kernel(
    const float* __restrict__ dti, vuint4* __restrict__ aos)
{
    const int bid = blockIdx.x;                    // 2048 blocks
    const int sb = ((bid & 7) << 8) | (bid >> 3);  // XCD i-slab swizzle
    const int id4 = (sb * 256 + (int)threadIdx.x) * 4;

    const vfloat4 v0 = __builtin_nontemporal_load(reinterpret_cast<const vfloat4*>(dti + 0 * NVOX + id4));
    const vfloat4 v1 = __builtin_nontemporal_load(reinterpret_cast<const vfloat4*>(dti + 1 * NVOX + id4));
    const vfloat4 v2 = __builtin_nontemporal_load(reinterpret_cast<const vfloat4*>(dti + 2 * NVOX + id4));
    const vfloat4 v3 = __builtin_nontemporal_load(reinterpret_cast<const vfloat4*>(dti + 3 * NVOX + id4));
    const vfloat4 v4 = __builtin_nontemporal_load(reinterpret_cast<const vfloat4*>(dti + 4 * NVOX + id4));
    const vfloat4 v5 = __builtin_nontemporal_load(reinterpret_cast<const vfloat4*>(dti + 5 * NVOX + id4));

    auto packone = [&](float a0, float a1, float a2, float a3, float a4,
                       float a5, int idx) {
        const __half2 h01 = __floats2half2_rn(a0, a1);
        const __half2 h23 = __floats2half2_rn(a2, a3);
        const __half2 h45 = __floats2half2_rn(a4, a5);
        vuint4 q;
        q.x = *reinterpret_cast<const unsigned int*>(&h01);
        q.y = *reinterpret_cast<const unsigned int*>(&h23);
        q.z = *reinterpret_cast<const unsigned int*>(&h45);
        q.w = 0u;
        aos[idx] = q;  // normal store: we WANT these lines in L2 for pass B
    };
    packone(v0.x, v1.x, v2.x, v3.x, v4.x, v5.x, id4 + 0);
    packone(v0.y, v1.y, v2.y, v3.y, v4.y, v5.y, id4 + 1);
    packone(v0.z, v1.z, v2.z, v3.z, v4.z, v5.z, id4 + 2);
    packone(v0.w, v1.w, v2.w, v3.w, v4.w, v5.w, id4 + 3);
}

// ---- fp32 polar factor: branch-free 3 scaled + 3 unscaled Newton ------------
// Fixed point: R = U @ Vh (SVD polar factor), sign(det) preserved.
// For cond<=2e3: scaled iters contract sigma-range 22 -> 2.5 -> 1.1, then
// unscaled e^2/2: 0.12 -> 7e-3 -> 2e-5 -> ~eps32.
// Returns bad=true for cond_F(J) > 2e3 (caller redoes in fp64).
__device__ __forceinline__ bool polar_f32(const float J[9], float X[9])
{
#pragma unroll
    for (int t = 0; t < 9; ++t) X[t] = J[t];
    bool bad = false;
#pragma unroll
    for (int it = 0; it < 6; ++it) {
        float C[9];
        C[0] = X[4] * X[8] - X[5] * X[7];
        C[1] = X[5] * X[6] - X[3] * X[8];
        C[2] = X[3] * X[7] - X[4] * X[6];
        C[3] = X[2] * X[7] - X[1] * X[8];
        C[4] = X[0] * X[8] - X[2] * X[6];
        C[5] = X[1] * X[6] - X[0] * X[7];
        C[6] = X[1] * X[5] - X[2] * X[4];
        C[7] = X[2] * X[3] - X[0] * X[5];
        C[8] = X[0] * X[4] - X[1] * X[3];
        const float det = X[0] * C[0] + X[1] * C[1] + X[2] * C[2];
        float a, b;
        if (it < 3) {
            float nX = 0.0f, nC = 0.0f;
#pragma unroll
            for (int t = 0; t < 9; ++t) { nX += X[t] * X[t]; nC += C[t] * C[t]; }
            if (it == 0)
                bad = !(nX * nC < 4.0e6f * det * det);  // condF > 2e3 (sqrt-free)
            // s = ||C||/||X||; r = 1/sqrt(s*|det|); a = 0.5*s*r = 0.5*g;
            // b = 0.5*r*sign(det)  (g = sqrt(s/|det|), b = 0.5/(g*det))
            const float s = __builtin_amdgcn_sqrtf(nC * __builtin_amdgcn_rcpf(nX));
            const float r = __builtin_amdgcn_rsqf(s * fabsf(det));
            a = 0.5f * s * r;
            b = copysignf(0.5f * r, det);
        } else {
            a = 0.5f;
            b = 0.5f * __builtin_amdgcn_rcpf(det);
        }
#pragma unroll
        for (int t = 0; t < 9; ++t) X[t] = a * X[t] + b * C[t];
    }
    return bad;
}

// ---- fp64 fallback (rare; inline & unrolled => register-resident; a
// noinline call made these arrays addressable -> ~220MB scratch spill in R2) --
__device__ __forceinline__ void polar_f64(const float J[9], float X[9])
{
    double Y[9];
#pragma unroll
    for (int t = 0; t < 9; ++t) Y[t] = (double)J[t];
    for (int it = 0; it < 20; ++it) {
        double C[9];
        C[0] = Y[4] * Y[8] - Y[5] * Y[7];
        C[1] = Y[5] * Y[6] - Y[3] * Y[8];
        C[2] = Y[3] * Y[7] - Y[4] * Y[6];
        C[3] = Y[2] * Y[7] - Y[1] * Y[8];
        C[4] = Y[0] * Y[8] - Y[2] * Y[6];
        C[5] = Y[1] * Y[6] - Y[0] * Y[7];
        C[6] = Y[1] * Y[5] - Y[2] * Y[4];
        C[7] = Y[2] * Y[3] - Y[0] * Y[5];
        C[8] = Y[0] * Y[4] - Y[1] * Y[3];
        const double det = Y[0] * C[0] + Y[1] * C[1] + Y[2] * C[2];
        if (!(fabs(det) > 1e-300)) break;
        double nX = 0.0, nC = 0.0;
#pragma unroll
        for (int t = 0; t < 9; ++t) { nX += Y[t] * Y[t]; nC += C[t] * C[t]; }
        const double g = sqrt(sqrt(nC) / (fabs(det) * sqrt(nX)));
        const double a = 0.5 * g;
        const double b = 0.5 / (g * det);
        double diff2 = 0.0, n2 = 0.0;
#pragma unroll
        for (int t = 0; t < 9; ++t) {
            const double y = a * Y[t] + b * C[t];
            const double d = y - Y[t];
            diff2 += d * d; n2 += y * y;
            Y[t] = y;
        }
        if (diff2 <= 1e-26 * n2) break;
    }
#pragma unroll
    for (int t = 0; t < 9; ++t) X[t] = (float)Y[t];
}

// ---------------- Pass B: warp + polar + congruence --------------------------
__global__ __launch_bounds__(256) void warp_dti_kernel(
    const vuint4* __restrict__ aos,
    const float* __restrict__ ddf,
    float* __restrict__ out)
{
    const int bid = blockIdx.x;                     // 8192 blocks
    const int sb = ((bid & 7) << 10) | (bid >> 3);  // XCD i-slab swizzle
    const int id = sb * 256 + (int)threadIdx.x;
    const int k = id & (DIM - 1);
    const int j = (id >> 7) & (DIM - 1);
    const int i = id >> 14;

    // ---- Jacobian: J = I + grad(ddf) (np.gradient semantics) ----
    const int im = (i > 0) ? i - 1 : 0, ip = (i < DIM - 1) ? i + 1 : DIM - 1;
    const int jm = (j > 0) ? j - 1 : 0, jp = (j < DIM - 1) ? j + 1 : DIM - 1;
    const int km = (k > 0) ? k - 1 : 0, kp = (k < DIM - 1) ? k + 1 : DIM - 1;
    const float si = (ip - im == 2) ? 0.5f : 1.0f;
    const float sj = (jp - jm == 2) ? 0.5f : 1.0f;
    const float sk = (kp - km == 2) ? 0.5f : 1.0f;

    const int l_ip = (ip << 14) | (j << 7) | k;
    const int l_im = (im << 14) | (j << 7) | k;
    const int l_jp = (i << 14) | (jp << 7) | k;
    const int l_jm = (i << 14) | (jm << 7) | k;
    const int l_kp = (i << 14) | (j << 7) | kp;
    const int l_km = (i << 14) | (j << 7) | km;

    float J[9];
    float u[3];
#pragma unroll
    for (int c = 0; c < 3; ++c) {
        const float* __restrict__ p = ddf + c * NVOX;
        u[c] = p[id];
        J[c * 3 + 0] = (p[l_ip] - p[l_im]) * si;
        J[c * 3 + 1] = (p[l_jp] - p[l_jm]) * sj;
        J[c * 3 + 2] = (p[l_kp] - p[l_km]) * sk;
        J[c * 3 + c] += 1.0f;
    }

    // ---- Trilinear warp from fp16 AoS (border padding) ----
    const float cx = fminf(fmaxf((float)i + u[0], 0.0f), (float)(DIM - 1));
    const float cy = fminf(fmaxf((float)j + u[1], 0.0f), (float)(DIM - 1));
    const float cz = fminf(fmaxf((float)k + u[2], 0.0f), (float)(DIM - 1));
    const float x0f = floorf(cx), y0f = floorf(cy), z0f = floorf(cz);
    const float fx = cx - x0f, fy = cy - y0f, fz = cz - z0f;
    const int x0 = (int)x0f, y0 = (int)y0f, z0 = (int)z0f;
    const int x1 = min(x0 + 1, DIM - 1);
    const int y1 = min(y0 + 1, DIM - 1);
    const int z1 = min(z0 + 1, DIM - 1);

    const float gx0 = 1.0f - fx, gy0 = 1.0f - fy, gz0 = 1.0f - fz;

    // delta addressing: corners = base + {0,dz} + {0,dy} + {0,dx}
    const int dz = z1 - z0;
    const int dy = (y1 - y0) << 7;
    const int dx = (x1 - x0) << 14;
    const int b000 = (x0 << 14) | (y0 << 7) | z0;

    float acc0 = 0.0f, acc1 = 0.0f, acc2 = 0.0f;
    float acc3 = 0.0f, acc4 = 0.0f, acc5 = 0.0f;

    // fmaf((float)half, wt, acc) folds to v_fma_mix_f32 (f32 accumulate,
    // no separate v_cvt).
    auto gat = [&](int lin, float wt) {
        const vuint4 q = aos[lin];
        const unsigned int qx = q.x, qy = q.y, qz = q.z;
        const __half2 h01 = *reinterpret_cast<const __half2*>(&qx);
        const __half2 h23 = *reinterpret_cast<const __half2*>(&qy);
        const __half2 h45 = *reinterpret_cast<const __half2*>(&qz);
        acc0 = fmaf(__half2float(__low2half(h01)), wt, acc0);
        acc1 = fmaf(__half2float(__high2half(h01)), wt, acc1);
        acc2 = fmaf(__half2float(__low2half(h23)), wt, acc2);
        acc3 = fmaf(__half2float(__high2half(h23)), wt, acc3);
        acc4 = fmaf(__half2float(__low2half(h45)), wt, acc4);
        acc5 = fmaf(__half2float(__high2half(h45)), wt, acc5);
    };

    gat(b000,                gx0 * gy0 * gz0);
    gat(b000 + dz,           gx0 * gy0 * fz);
    gat(b000 + dy,           gx0 * fy * gz0);
    gat(b000 + dy + dz,      gx0 * fy * fz);
    gat(b000 + dx,           fx * gy0 * gz0);
    gat(b000 + dx + dz,      fx * gy0 * fz);
    gat(b000 + dx + dy,      fx * fy * gz0);
    gat(b000 + dx + dy + dz, fx * fy * fz);

    // ---- Polar factor ----
    float X[9];
    const bool bad = polar_f32(J, X);
    if (__builtin_expect(bad, 0)) polar_f64(J, X);

    // ---- Dp = R^T M R ----
    const float M00 = acc0, M01 = acc1, M11 = acc2;
    const float M02 = acc3, M12 = acc4, M22 = acc5;
    float P[9];  // P = M * R
    P[0] = M00 * X[0] + M01 * X[3] + M02 * X[6];
    P[1] = M00 * X[1] + M01 * X[4] + M02 * X[7];
    P[2] = M00 * X[2] + M01 * X[5] + M02 * X[8];
    P[3] = M01 * X[0] + M11 * X[3] + M12 * X[6];
    P[4] = M01 * X[1] + M11 * X[4] + M12 * X[7];
    P[5] = M01 * X[2] + M11 * X[5] + M12 * X[8];
    P[6] = M02 * X[0] + M12 * X[3] + M22 * X[6];
    P[7] = M02 * X[1] + M12 * X[4] + M22 * X[7];
    P[8] = M02 * X[2] + M12 * X[5] + M22 * X[8];

    // Output: 48 MB, zero reuse -> non-temporal so it doesn't evict aos
    // from L2/L3 between gathers.
    __builtin_nontemporal_store(X[0] * P[0] + X[3] * P[3] + X[6] * P[6], &out[0 * NVOX + id]);
    __builtin_nontemporal_store(X[1] * P[0] + X[4] * P[3] + X[7] * P[6], &out[1 * NVOX + id]);
    __builtin_nontemporal_store(X[1] * P[1] + X[4] * P[4] + X[7] * P[7], &out[2 * NVOX + id]);
    __builtin_nontemporal_store(X[2] * P[0] + X[5] * P[3] + X[8] * P[6], &out[3 * NVOX + id]);
    __builtin_nontemporal_store(X[2] * P[1] + X[5] * P[4] + X[8] * P[7], &out[4 * NVOX + id]);
    __builtin_nontemporal_store(X[2] * P[2] + X[5] * P[5] + X[8] * P[8], &out[5 * NVOX + id]);
}

extern "C" void kernel_launch(void* const* d_in, const int* in_sizes, int n_in,
                              void* d_out, int out_size, void* d_ws, size_t ws_size,
                              hipStream_t stream) {
    const float* dti = (const float*)d_in[0];
    const float* ddf = (const float*)d_in[1];
    float* out = (float*)d_out;
    vuint4* aos = (vuint4*)d_ws;  // 2M voxels * 16 B = 32 MB scratch

    hipLaunchKernelGGL(pack_dti_kernel, dim3(NVOX / 1024), dim3(256), 0, stream,
                       dti, aos);
    hipLaunchKernelGGL(warp_dti_kernel, dim3(NVOX / 256), dim3(256), 0, stream,
                       aos, ddf, out);
}